// Round 1
// baseline (1153.520 us; speedup 1.0000x reference)
//
#include <hip/hip_runtime.h>
#include <hip/hip_bf16.h>

#define RES   100
#define ITERS 1000
#define P     100          // LDS row pitch (floats)
// halo layout: rows 0..101, idx(i,j) = (i+1)*P + j  (i = physical row)

// ---------------- small FC layers (relu) ----------------
__global__ __launch_bounds__(256) void fc_relu(const float* __restrict__ X,
                                               const float* __restrict__ W,
                                               const float* __restrict__ bias,
                                               float* __restrict__ Y,
                                               int B, int K, int N) {
    int t = blockIdx.x * 256 + threadIdx.x;
    if (t >= B * N) return;
    int b = t / N, n = t % N;          // N is a power of two here
    const float* x = X + b * K;
    float acc = bias[n];
    for (int k = 0; k < K; ++k)
        acc = fmaf(x[k], W[k * N + n], acc);
    Y[t] = fmaxf(acc, 0.0f);
}

// ---------------- layer 4 fused: gen + residual conductivity + clamp ----------------
// grid (40, 2): blockIdx.x = j-chunk of 256 columns, blockIdx.y = batch half (16 samples)
__global__ __launch_bounds__(256) void fc4_fused(const float* __restrict__ X3,
                                                 const float* __restrict__ W4,
                                                 const float* __restrict__ b4,
                                                 const float* __restrict__ pores,
                                                 float* __restrict__ cond) {
    __shared__ float xs[16 * 512];
    const int bg = blockIdx.y;                 // sample group
    // stage X3 slice (16 x 512 = 32 KB)
    for (int i = threadIdx.x; i < 16 * 512; i += 256)
        xs[i] = X3[bg * 16 * 512 + i];
    __syncthreads();

    int j = blockIdx.x * 256 + threadIdx.x;
    if (j >= RES * RES) return;

    float acc[16];
    float bj = b4[j];
#pragma unroll
    for (int b = 0; b < 16; ++b) acc[b] = bj;

#pragma unroll 4
    for (int k = 0; k < 512; ++k) {
        float w = W4[k * (RES * RES) + j];
#pragma unroll
        for (int b = 0; b < 16; ++b)
            acc[b] = fmaf(xs[b * 512 + k], w, acc[b]);
    }

    int row = j / RES, col = j % RES;
    int p = (row / 20) * 5 + (col / 20);       // coarse 5x5 pore cell
#pragma unroll
    for (int b = 0; b < 16; ++b) {
        int bb = bg * 16 + b;
        float base = 1.0f - pores[bb * 25 + p];
        cond[bb * RES * RES + j] = fmaxf(acc[b] + base, 0.01f);
    }
}

// ---------------- Jacobi solve: one workgroup per sample ----------------
__global__ __launch_bounds__(1024) void jacobi(const float* __restrict__ cond,
                                               float* __restrict__ kappa_out) {
    __shared__ float bufA[102 * P];
    __shared__ float bufB[102 * P];
    __shared__ float red[RES];

    const int b   = blockIdx.x;
    const int tid = threadIdx.x;
    const float* kk = cond + b * RES * RES;

    // stage conductivity into bufA center
    for (int i = tid; i < RES * RES; i += 1024)
        bufA[P + i] = kk[i];                    // (i/100 + 1)*P + i%100 == P + i
    __syncthreads();

    const int  s      = tid / 100;              // strip id 0..9
    const int  j      = tid - s * 100;          // column 0..99
    const bool active = (tid < 1000);

    float wN[10], wS[10], wW[10], wE[10], T[10];
    float k0 = 0.0f;

    if (active) {
        const int i0 = s * 10;
#pragma unroll
        for (int r = 0; r < 10; ++r) {
            int i  = i0 + r;
            int in_ = (i == 0)      ? i : i - 1;
            int is_ = (i == RES-1)  ? i : i + 1;
            int jw  = (j == 0)      ? j : j - 1;
            int je  = (j == RES-1)  ? j : j + 1;
            float kc = bufA[(i + 1) * P + j];
            float kn = 0.5f * (kc + bufA[(in_ + 1) * P + j]);
            float ks = 0.5f * (kc + bufA[(is_ + 1) * P + j]);
            float kw = 0.5f * (kc + bufA[(i + 1) * P + jw]);
            float ke = 0.5f * (kc + bufA[(i + 1) * P + je]);
            float inv = 1.0f / (kn + ks + kw + ke + 1e-12f);
            wN[r] = kn * inv; wS[r] = ks * inv; wW[r] = kw * inv; wE[r] = ke * inv;
            if (i == 0) k0 = kc;
        }
    }
    __syncthreads();

    // init T (linspace 1..0 along rows) + halos in both buffers
    if (active) {
        const int i0 = s * 10;
#pragma unroll
        for (int r = 0; r < 10; ++r) {
            int i = i0 + r;
            T[r] = 1.0f - (float)i / (float)(RES - 1);
            bufA[(i + 1) * P + j] = T[r];
        }
        if (s == 0) { bufA[j] = 1.0f; bufB[j] = 1.0f; }                     // top Dirichlet halo
        if (s == 9) { bufA[101 * P + j] = 0.0f; bufB[101 * P + j] = 0.0f; } // bottom Dirichlet halo
    }
    __syncthreads();

    const int base = (s * 10 + 1) * P + j;      // byte-offset-friendly LDS base

#pragma unroll 2
    for (int it = 0; it < ITERS; ++it) {
        float* src = (it & 1) ? bufB : bufA;
        float* dst = (it & 1) ? bufA : bufB;
        if (active) {
            float Tn[10];
#pragma unroll
            for (int r = 0; r < 10; ++r) {
                float north = (r == 0) ? src[base - P]      : T[r - 1];
                float south = (r == 9) ? src[base + 10 * P] : T[r + 1];
                float west  = (j == 0)     ? T[r] : src[base + r * P - 1];
                float east  = (j == RES-1) ? T[r] : src[base + r * P + 1];
                Tn[r] = wN[r] * north + wS[r] * south + wW[r] * west + wE[r] * east;
            }
#pragma unroll
            for (int r = 0; r < 10; ++r) {
                T[r] = Tn[r];
                dst[base + r * P] = Tn[r];
            }
        }
        __syncthreads();
    }

    // kappa = mean_j 2*res*k[0][j]*(1 - T[0][j])
    if (active && s == 0)
        red[j] = 2.0f * (float)RES * k0 * (1.0f - T[0]);
    __syncthreads();
    if (tid == 0) {
        float sum = 0.0f;
        for (int jj = 0; jj < RES; ++jj) sum += red[jj];
        kappa_out[b] = sum * (1.0f / (float)RES);
    }
}

extern "C" void kernel_launch(void* const* d_in, const int* in_sizes, int n_in,
                              void* d_out, int out_size, void* d_ws, size_t ws_size,
                              hipStream_t stream) {
    (void)in_sizes; (void)n_in; (void)out_size; (void)ws_size;
    const float* pores = (const float*)d_in[0];
    const float* W1 = (const float*)d_in[1];
    const float* b1 = (const float*)d_in[2];
    const float* W2 = (const float*)d_in[3];
    const float* b2 = (const float*)d_in[4];
    const float* W3 = (const float*)d_in[5];
    const float* b3 = (const float*)d_in[6];
    const float* W4 = (const float*)d_in[7];
    const float* b4 = (const float*)d_in[8];

    float* ws = (float*)d_ws;
    float* x1 = ws;                 // 32*128
    float* x2 = x1 + 32 * 128;      // 32*256
    float* x3 = x2 + 32 * 256;      // 32*512

    float* kappa = (float*)d_out;           // 32
    float* cond  = kappa + 32;              // 32*100*100

    fc_relu<<<(32 * 128 + 255) / 256, 256, 0, stream>>>(pores, W1, b1, x1, 32, 25, 128);
    fc_relu<<<(32 * 256 + 255) / 256, 256, 0, stream>>>(x1,    W2, b2, x2, 32, 128, 256);
    fc_relu<<<(32 * 512 + 255) / 256, 256, 0, stream>>>(x2,    W3, b3, x3, 32, 256, 512);
    fc4_fused<<<dim3(40, 2), 256, 0, stream>>>(x3, W4, b4, pores, cond);
    jacobi<<<32, 1024, 0, stream>>>(cond, kappa);
}

// Round 2
// 968.970 us; speedup vs baseline: 1.1905x; 1.1905x over previous
//
#include <hip/hip_runtime.h>
#include <hip/hip_bf16.h>

#define RES   100
#define ITERS 1000
#define SLOTP 128            // floats per LDS boundary-row slot (512 B, b64-friendly)

// ---------------- small FC layers (relu) ----------------
__global__ __launch_bounds__(256) void fc_relu(const float* __restrict__ X,
                                               const float* __restrict__ W,
                                               const float* __restrict__ bias,
                                               float* __restrict__ Y,
                                               int B, int K, int N) {
    int t = blockIdx.x * 256 + threadIdx.x;
    if (t >= B * N) return;
    int b = t / N, n = t % N;
    const float* x = X + b * K;
    float acc = bias[n];
    for (int k = 0; k < K; ++k)
        acc = fmaf(x[k], W[k * N + n], acc);
    Y[t] = fmaxf(acc, 0.0f);
}

// ---------------- layer 4 fused: gen + residual conductivity + clamp ----------------
__global__ __launch_bounds__(256) void fc4_fused(const float* __restrict__ X3,
                                                 const float* __restrict__ W4,
                                                 const float* __restrict__ b4,
                                                 const float* __restrict__ pores,
                                                 float* __restrict__ cond) {
    __shared__ float xs[16 * 512];
    const int bg = blockIdx.y;
    for (int i = threadIdx.x; i < 16 * 512; i += 256)
        xs[i] = X3[bg * 16 * 512 + i];
    __syncthreads();

    int j = blockIdx.x * 256 + threadIdx.x;
    if (j >= RES * RES) return;

    float acc[16];
    float bj = b4[j];
#pragma unroll
    for (int b = 0; b < 16; ++b) acc[b] = bj;

#pragma unroll 4
    for (int k = 0; k < 512; ++k) {
        float w = W4[k * (RES * RES) + j];
#pragma unroll
        for (int b = 0; b < 16; ++b)
            acc[b] = fmaf(xs[b * 512 + k], w, acc[b]);
    }

    int row = j / RES, col = j % RES;
    int p = (row / 20) * 5 + (col / 20);
#pragma unroll
    for (int b = 0; b < 16; ++b) {
        int bb = bg * 16 + b;
        float base = 1.0f - pores[bb * 25 + p];
        cond[bb * RES * RES + j] = fmaxf(acc[b] + base, 0.01f);
    }
}

// ---------------- Jacobi solve: DPP register-exchange version ----------------
// One WG (1024 thr = 16 waves) per sample. Lane l owns cols (2l, 2l+1) as float2
// (lanes 0..49 real, 50..63 compute duplicates into slot padding). Wave w owns a
// row band (w<4: 7 rows, else 6). W/E neighbors via dpp wave_shr1/wave_shl1;
// N/S via registers except band boundaries, published to LDS slots.
// LDS slots per buffer: slot 2w = band-top row, 2w+1 = band-bottom row,
// slot 32 = const 1.0 (top Dirichlet), slot 33 = const 0.0 (bottom Dirichlet).

__device__ __forceinline__ float dpp_shr1(float old_v, float src) {  // lane i <- src[i-1]
    return __int_as_float(__builtin_amdgcn_update_dpp(
        __float_as_int(old_v), __float_as_int(src), 0x138, 0xf, 0xf, false));
}
__device__ __forceinline__ float dpp_shl1(float old_v, float src) {  // lane i <- src[i+1]
    return __int_as_float(__builtin_amdgcn_update_dpp(
        __float_as_int(old_v), __float_as_int(src), 0x130, 0xf, 0xf, false));
}

template<int R>
__device__ __forceinline__ void jstep(const float* src, float* dst,
                                      const float2* wN, const float2* wS,
                                      const float2* wW, const float2* wE,
                                      const float2* Tin, float2* Tout,
                                      int nslot, int sslot, int topslot,
                                      int lane2, bool fix49) {
    float2 nval = *(const float2*)(src + nslot * SLOTP + lane2);
    float2 sval = *(const float2*)(src + sslot * SLOTP + lane2);
#pragma unroll
    for (int r = 0; r < R; ++r) {
        float2 nb = (r == 0)     ? nval : Tin[r - 1];
        float2 sb = (r == R - 1) ? sval : Tin[r + 1];
        float lo = Tin[r].x, hi = Tin[r].y;
        float wlo = dpp_shr1(lo, hi);            // west of col 2l = hi[l-1]; lane0 -> lo (Neumann)
        float ehi = dpp_shl1(hi, lo);            // east of col 2l+1 = lo[l+1]; lane63 -> hi
        ehi = fix49 ? hi : ehi;                  // col 99 mirror: east = self
        float tlo = fmaf(wN[r].x, nb.x, fmaf(wS[r].x, sb.x,
                    fmaf(wW[r].x, wlo, wE[r].x * hi)));
        float thi = fmaf(wN[r].y, nb.y, fmaf(wS[r].y, sb.y,
                    fmaf(wW[r].y, lo,  wE[r].y * ehi)));
        Tout[r] = make_float2(tlo, thi);
    }
    *(float2*)(dst + topslot * SLOTP + lane2)       = Tout[0];
    *(float2*)(dst + (topslot + 1) * SLOTP + lane2) = Tout[R - 1];
}

__global__ __launch_bounds__(1024) void jacobi(const float* __restrict__ cond,
                                               float* __restrict__ kappa_out) {
    __shared__ float kst[RES * RES];        // staged conductivity
    __shared__ float SA[34 * SLOTP];
    __shared__ float SB[34 * SLOTP];

    const int b   = blockIdx.x;
    const int tid = threadIdx.x;

    for (int i = tid; i < RES * RES; i += 1024)
        kst[i] = cond[b * RES * RES + i];
    if (tid < SLOTP) {
        SA[32 * SLOTP + tid] = 1.0f;  SA[33 * SLOTP + tid] = 0.0f;
        SB[32 * SLOTP + tid] = 1.0f;  SB[33 * SLOTP + tid] = 0.0f;
    }
    __syncthreads();

    const int w    = tid >> 6;
    const int lane = tid & 63;
    const int R    = (w < 4) ? 7 : 6;
    const int r0   = (w < 4) ? 7 * w : 28 + 6 * (w - 4);
    const int c0   = min(2 * lane, 98), c1 = c0 + 1;
    const int lane2 = 2 * lane;
    const bool fix49 = (lane == 49);

    float2 wN[7], wS[7], wW[7], wE[7], T0[7], T1[7];

#pragma unroll
    for (int r = 0; r < 7; ++r) {
        if (r < R) {
            int i   = r0 + r;
            int in_ = i ? i - 1 : 0;
            int is_ = (i < RES - 1) ? i + 1 : RES - 1;
            int jw  = c0 ? c0 - 1 : 0;
            int je  = (c1 < RES - 1) ? c1 + 1 : RES - 1;
            float kc0 = kst[i * RES + c0], kc1 = kst[i * RES + c1];
            float kn0 = 0.5f * (kc0 + kst[in_ * RES + c0]);
            float kn1 = 0.5f * (kc1 + kst[in_ * RES + c1]);
            float ks0 = 0.5f * (kc0 + kst[is_ * RES + c0]);
            float ks1 = 0.5f * (kc1 + kst[is_ * RES + c1]);
            float kw0 = 0.5f * (kc0 + kst[i * RES + jw]);
            float kw1 = 0.5f * (kc1 + kc0);
            float ke0 = 0.5f * (kc0 + kc1);
            float ke1 = 0.5f * (kc1 + kst[i * RES + je]);
            float inv0 = 1.0f / (kn0 + ks0 + kw0 + ke0 + 1e-12f);
            float inv1 = 1.0f / (kn1 + ks1 + kw1 + ke1 + 1e-12f);
            wN[r] = make_float2(kn0 * inv0, kn1 * inv1);
            wS[r] = make_float2(ks0 * inv0, ks1 * inv1);
            wW[r] = make_float2(kw0 * inv0, kw1 * inv1);
            wE[r] = make_float2(ke0 * inv0, ke1 * inv1);
            float v = 1.0f - (float)i * (1.0f / (RES - 1));
            T0[r] = make_float2(v, v);
        }
    }

    // publish initial boundary rows into SA
    float2 bot0 = (w < 4) ? T0[6] : T0[5];
    *(float2*)(SA + (2 * w) * SLOTP + lane2)     = T0[0];
    *(float2*)(SA + (2 * w + 1) * SLOTP + lane2) = bot0;
    __syncthreads();

    const int nslot = (w == 0)  ? 32 : (2 * w - 1);
    const int sslot = (w == 15) ? 33 : (2 * w + 2);
    const int topsl = 2 * w;

    for (int it = 0; it < ITERS / 2; ++it) {
        if (w < 4) jstep<7>(SA, SB, wN, wS, wW, wE, T0, T1, nslot, sslot, topsl, lane2, fix49);
        else       jstep<6>(SA, SB, wN, wS, wW, wE, T0, T1, nslot, sslot, topsl, lane2, fix49);
        __syncthreads();
        if (w < 4) jstep<7>(SB, SA, wN, wS, wW, wE, T1, T0, nslot, sslot, topsl, lane2, fix49);
        else       jstep<6>(SB, SA, wN, wS, wW, wE, T1, T0, nslot, sslot, topsl, lane2, fix49);
        __syncthreads();
    }

    // kappa = mean_j 2*res*k[0][j]*(1 - T[0][j]) = 2 * sum_lanes k*(1-T)
    if (w == 0) {
        float s = 0.0f;
        if (lane < 50)
            s = kst[c0] * (1.0f - T0[0].x) + kst[c1] * (1.0f - T0[0].y);
        for (int off = 32; off; off >>= 1)
            s += __shfl_down(s, off);
        if (lane == 0) kappa_out[b] = 2.0f * s;
    }
}

extern "C" void kernel_launch(void* const* d_in, const int* in_sizes, int n_in,
                              void* d_out, int out_size, void* d_ws, size_t ws_size,
                              hipStream_t stream) {
    (void)in_sizes; (void)n_in; (void)out_size; (void)ws_size;
    const float* pores = (const float*)d_in[0];
    const float* W1 = (const float*)d_in[1];
    const float* b1 = (const float*)d_in[2];
    const float* W2 = (const float*)d_in[3];
    const float* b2 = (const float*)d_in[4];
    const float* W3 = (const float*)d_in[5];
    const float* b3 = (const float*)d_in[6];
    const float* W4 = (const float*)d_in[7];
    const float* b4 = (const float*)d_in[8];

    float* ws = (float*)d_ws;
    float* x1 = ws;                 // 32*128
    float* x2 = x1 + 32 * 128;      // 32*256
    float* x3 = x2 + 32 * 256;      // 32*512

    float* kappa = (float*)d_out;           // 32
    float* cond  = kappa + 32;              // 32*100*100

    fc_relu<<<(32 * 128 + 255) / 256, 256, 0, stream>>>(pores, W1, b1, x1, 32, 25, 128);
    fc_relu<<<(32 * 256 + 255) / 256, 256, 0, stream>>>(x1,    W2, b2, x2, 32, 128, 256);
    fc_relu<<<(32 * 512 + 255) / 256, 256, 0, stream>>>(x2,    W3, b3, x3, 32, 256, 512);
    fc4_fused<<<dim3(40, 2), 256, 0, stream>>>(x3, W4, b4, pores, cond);
    jacobi<<<32, 1024, 0, stream>>>(cond, kappa);
}

// Round 3
// 646.997 us; speedup vs baseline: 1.7829x; 1.4976x over previous
//
#include <hip/hip_runtime.h>
#include <hip/hip_bf16.h>

#define RES   100
#define ITERS 1000
#define SLOTP 128            // floats per LDS boundary-row slot

typedef float vf2 __attribute__((ext_vector_type(2)));

// ---------------- fused MLP layers 1-3 ----------------
__global__ __launch_bounds__(256) void mlp123(const float* __restrict__ pores,
                                              const float* __restrict__ W1, const float* __restrict__ b1,
                                              const float* __restrict__ W2, const float* __restrict__ b2,
                                              const float* __restrict__ W3, const float* __restrict__ b3,
                                              float* __restrict__ x3out) {
    __shared__ float x1[128];
    __shared__ float x2[256];
    const int s = blockIdx.x, tid = threadIdx.x;

    if (tid < 128) {
        float acc = b1[tid];
#pragma unroll
        for (int k = 0; k < 25; ++k)
            acc = fmaf(pores[s * 25 + k], W1[k * 128 + tid], acc);
        x1[tid] = fmaxf(acc, 0.0f);
    }
    __syncthreads();

    {
        float acc = b2[tid];
#pragma unroll 8
        for (int k = 0; k < 128; ++k)
            acc = fmaf(x1[k], W2[k * 256 + tid], acc);
        x2[tid] = fmaxf(acc, 0.0f);
    }
    __syncthreads();

    {
        float a0 = b3[tid], a1 = b3[tid + 256];
#pragma unroll 8
        for (int k = 0; k < 256; ++k) {
            float xv = x2[k];
            a0 = fmaf(xv, W3[k * 512 + tid],       a0);
            a1 = fmaf(xv, W3[k * 512 + tid + 256], a1);
        }
        x3out[s * 512 + tid]       = fmaxf(a0, 0.0f);
        x3out[s * 512 + tid + 256] = fmaxf(a1, 0.0f);
    }
}

// ---------------- layer 4: gen + residual + clamp, ILP-pipelined ----------------
// grid (40, 4): 256 j's per WG, 8 samples per bg
__global__ __launch_bounds__(256) void fc4_fused(const float* __restrict__ X3,
                                                 const float* __restrict__ W4,
                                                 const float* __restrict__ b4,
                                                 const float* __restrict__ pores,
                                                 float* __restrict__ cond) {
    const int j = blockIdx.x * 256 + threadIdx.x;
    if (j >= RES * RES) return;
    const int bg = blockIdx.y;
    const float* x = X3 + bg * 8 * 512;      // uniform-address reads -> SMEM path

    float acc[8];
    float bj = b4[j];
#pragma unroll
    for (int b = 0; b < 8; ++b) acc[b] = bj;

    for (int k0 = 0; k0 < 512; k0 += 8) {
        float w[8];
#pragma unroll
        for (int u = 0; u < 8; ++u)
            w[u] = W4[(k0 + u) * (RES * RES) + j];
#pragma unroll
        for (int u = 0; u < 8; ++u) {
#pragma unroll
            for (int b = 0; b < 8; ++b)
                acc[b] = fmaf(x[b * 512 + k0 + u], w[u], acc[b]);
        }
    }

    const int row = j / RES, col = j % RES;
    const int p = (row / 20) * 5 + (col / 20);
#pragma unroll
    for (int b = 0; b < 8; ++b) {
        int bb = bg * 8 + b;
        float base = 1.0f - pores[bb * 25 + p];
        cond[bb * RES * RES + j] = fmaxf(acc[b] + base, 0.01f);
    }
}

// ---------------- Jacobi solve: DPP + packed-fp32 version ----------------
__device__ __forceinline__ float dpp_shr1(float old_v, float src) {  // lane i <- src[i-1]
    return __int_as_float(__builtin_amdgcn_update_dpp(
        __float_as_int(old_v), __float_as_int(src), 0x138, 0xf, 0xf, false));
}
__device__ __forceinline__ float dpp_shl1(float old_v, float src) {  // lane i <- src[i+1]
    return __int_as_float(__builtin_amdgcn_update_dpp(
        __float_as_int(old_v), __float_as_int(src), 0x130, 0xf, 0xf, false));
}

// Update: Tnew = wN*nb + wS*sb + wA*{wlo,ehi} + wB*{hi,lo}
//  .x: kn0*N + ks0*S + kw0*wlo + ke0*hi   (wA.x=kw0, wB.x=ke0)
//  .y: kn1*N + ks1*S + ke1*ehi + kw1*lo   (wA.y=ke1, wB.y=kw1)
template<int R>
__device__ __forceinline__ void jstep(const vf2* __restrict__ nptr, const vf2* __restrict__ sptr,
                                      vf2* __restrict__ topptr, vf2* __restrict__ botptr,
                                      const vf2* wN, const vf2* wS,
                                      const vf2* wA, const vf2* wB,
                                      const vf2* Tin, vf2* Tout, bool fix49) {
    vf2 nval = *nptr;
    vf2 sval = *sptr;
#pragma unroll
    for (int r = 0; r < R; ++r) {
        vf2 nb = (r == 0)     ? nval : Tin[r - 1];
        vf2 sb = (r == R - 1) ? sval : Tin[r + 1];
        float lo = Tin[r].x, hi = Tin[r].y;
        float wlo = dpp_shr1(lo, hi);
        float ehi = dpp_shl1(hi, lo);
        ehi = fix49 ? hi : ehi;
        vf2 P1; P1.x = wlo; P1.y = ehi;
        vf2 TS; TS.x = hi;  TS.y = lo;
        Tout[r] = wN[r] * nb + wS[r] * sb + wA[r] * P1 + wB[r] * TS;
    }
    *topptr = Tout[0];
    *botptr = Tout[R - 1];
}

__global__ __launch_bounds__(1024) void jacobi(const float* __restrict__ cond,
                                               float* __restrict__ kappa_out) {
    __shared__ float kst[RES * RES];
    __shared__ float SA[34 * SLOTP];
    __shared__ float SB[34 * SLOTP];

    const int b   = blockIdx.x;
    const int tid = threadIdx.x;

    for (int i = tid; i < RES * RES; i += 1024)
        kst[i] = cond[b * RES * RES + i];
    if (tid < SLOTP) {
        SA[32 * SLOTP + tid] = 1.0f;  SA[33 * SLOTP + tid] = 0.0f;
        SB[32 * SLOTP + tid] = 1.0f;  SB[33 * SLOTP + tid] = 0.0f;
    }
    __syncthreads();

    const int w    = tid >> 6;
    const int lane = tid & 63;
    const int R    = (w < 4) ? 7 : 6;
    const int r0   = (w < 4) ? 7 * w : 28 + 6 * (w - 4);
    const int c0   = min(2 * lane, 98), c1 = c0 + 1;
    const int lane2 = 2 * lane;
    const bool fix49 = (lane == 49);

    vf2 wN[7], wS[7], wA[7], wB[7], T0[7], T1[7];

#pragma unroll
    for (int r = 0; r < 7; ++r) {
        if (r < R) {
            int i   = r0 + r;
            int in_ = i ? i - 1 : 0;
            int is_ = (i < RES - 1) ? i + 1 : RES - 1;
            int jw  = c0 ? c0 - 1 : 0;
            int je  = (c1 < RES - 1) ? c1 + 1 : RES - 1;
            float kc0 = kst[i * RES + c0], kc1 = kst[i * RES + c1];
            float kn0 = 0.5f * (kc0 + kst[in_ * RES + c0]);
            float kn1 = 0.5f * (kc1 + kst[in_ * RES + c1]);
            float ks0 = 0.5f * (kc0 + kst[is_ * RES + c0]);
            float ks1 = 0.5f * (kc1 + kst[is_ * RES + c1]);
            float kw0 = 0.5f * (kc0 + kst[i * RES + jw]);
            float kw1 = 0.5f * (kc1 + kc0);
            float ke0 = 0.5f * (kc0 + kc1);
            float ke1 = 0.5f * (kc1 + kst[i * RES + je]);
            float inv0 = 1.0f / (kn0 + ks0 + kw0 + ke0 + 1e-12f);
            float inv1 = 1.0f / (kn1 + ks1 + kw1 + ke1 + 1e-12f);
            wN[r].x = kn0 * inv0;  wN[r].y = kn1 * inv1;
            wS[r].x = ks0 * inv0;  wS[r].y = ks1 * inv1;
            wA[r].x = kw0 * inv0;  wA[r].y = ke1 * inv1;
            wB[r].x = ke0 * inv0;  wB[r].y = kw1 * inv1;
            float v = 1.0f - (float)i * (1.0f / (RES - 1));
            T0[r].x = v;  T0[r].y = v;
        }
    }

    // publish initial boundary rows into SA
    vf2 bot0 = (w < 4) ? T0[6] : T0[5];
    *(vf2*)(SA + (2 * w) * SLOTP + lane2)     = T0[0];
    *(vf2*)(SA + (2 * w + 1) * SLOTP + lane2) = bot0;
    __syncthreads();

    const int nslot = (w == 0)  ? 32 : (2 * w - 1);
    const int sslot = (w == 15) ? 33 : (2 * w + 2);
    const int topsl = 2 * w;

    const vf2* SAn = (const vf2*)(SA + nslot * SLOTP + lane2);
    const vf2* SAs = (const vf2*)(SA + sslot * SLOTP + lane2);
    const vf2* SBn = (const vf2*)(SB + nslot * SLOTP + lane2);
    const vf2* SBs = (const vf2*)(SB + sslot * SLOTP + lane2);
    vf2* SAtop = (vf2*)(SA + topsl * SLOTP + lane2);
    vf2* SAbot = (vf2*)(SA + (topsl + 1) * SLOTP + lane2);
    vf2* SBtop = (vf2*)(SB + topsl * SLOTP + lane2);
    vf2* SBbot = (vf2*)(SB + (topsl + 1) * SLOTP + lane2);

    for (int it = 0; it < ITERS / 2; ++it) {
        if (w < 4) jstep<7>(SAn, SAs, SBtop, SBbot, wN, wS, wA, wB, T0, T1, fix49);
        else       jstep<6>(SAn, SAs, SBtop, SBbot, wN, wS, wA, wB, T0, T1, fix49);
        __syncthreads();
        if (w < 4) jstep<7>(SBn, SBs, SAtop, SAbot, wN, wS, wA, wB, T1, T0, fix49);
        else       jstep<6>(SBn, SBs, SAtop, SAbot, wN, wS, wA, wB, T1, T0, fix49);
        __syncthreads();
    }

    // kappa = mean_j 2*res*k[0][j]*(1 - T[0][j]) = 2 * sum_lanes k*(1-T)
    if (w == 0) {
        float s = 0.0f;
        if (lane < 50)
            s = kst[c0] * (1.0f - T0[0].x) + kst[c1] * (1.0f - T0[0].y);
        for (int off = 32; off; off >>= 1)
            s += __shfl_down(s, off);
        if (lane == 0) kappa_out[b] = 2.0f * s;
    }
}

extern "C" void kernel_launch(void* const* d_in, const int* in_sizes, int n_in,
                              void* d_out, int out_size, void* d_ws, size_t ws_size,
                              hipStream_t stream) {
    (void)in_sizes; (void)n_in; (void)out_size; (void)ws_size;
    const float* pores = (const float*)d_in[0];
    const float* W1 = (const float*)d_in[1];
    const float* b1 = (const float*)d_in[2];
    const float* W2 = (const float*)d_in[3];
    const float* b2 = (const float*)d_in[4];
    const float* W3 = (const float*)d_in[5];
    const float* b3 = (const float*)d_in[6];
    const float* W4 = (const float*)d_in[7];
    const float* b4 = (const float*)d_in[8];

    float* x3 = (float*)d_ws;               // 32*512

    float* kappa = (float*)d_out;           // 32
    float* cond  = kappa + 32;              // 32*100*100

    mlp123<<<32, 256, 0, stream>>>(pores, W1, b1, W2, b2, W3, b3, x3);
    fc4_fused<<<dim3(40, 4), 256, 0, stream>>>(x3, W4, b4, pores, cond);
    jacobi<<<32, 1024, 0, stream>>>(cond, kappa);
}